// Round 1
// baseline (248.054 us; speedup 1.0000x reference)
//
#include <hip/hip_runtime.h>
#include <hip/hip_bf16.h>

typedef __bf16 bf16x8 __attribute__((ext_vector_type(8)));
typedef float f32x4 __attribute__((ext_vector_type(4)));
typedef unsigned short u16x8 __attribute__((ext_vector_type(8)));

__device__ __forceinline__ unsigned short f2bf(float f) {
    unsigned int u = __builtin_bit_cast(unsigned int, f);
    unsigned int r = (u + 0x7FFFu + ((u >> 16) & 1u)) >> 16;
    return (unsigned short)r;
}

__device__ __forceinline__ void load_lds_16(const void* g, void* lds) {
    __builtin_amdgcn_global_load_lds(
        (const __attribute__((address_space(1))) unsigned int*)g,
        (__attribute__((address_space(3))) unsigned int*)lds, 16, 0, 0);
}

// ---------- 1) x fp32 -> bf16 ----------
__global__ void conv_x_kernel(const float* __restrict__ x, unsigned short* __restrict__ xb) {
    int i = blockIdx.x * 256 + threadIdx.x;   // 8 elems/thread, 12582912 total
    const float4* xp = (const float4*)x;
    float4 a = xp[i * 2];
    float4 c = xp[i * 2 + 1];
    u16x8 r;
    r[0] = f2bf(a.x); r[1] = f2bf(a.y); r[2] = f2bf(a.z); r[3] = f2bf(a.w);
    r[4] = f2bf(c.x); r[5] = f2bf(c.y); r[6] = f2bf(c.z); r[7] = f2bf(c.w);
    *(u16x8*)(xb + (size_t)i * 8) = r;
}

// ---------- 2) W_eff = W + 2*B@A  (fp32, [o][k]) ----------
__global__ void weff_kernel(const float* __restrict__ W, const float* __restrict__ A,
                            const float* __restrict__ B, float* __restrict__ Weff) {
    int o = blockIdx.x / 3;
    int k = (blockIdx.x % 3) * 256 + threadIdx.x;
    float acc = W[o * 768 + k];
#pragma unroll
    for (int r = 0; r < 8; ++r) acc += 2.0f * B[o * 8 + r] * A[r * 768 + k];
    Weff[o * 768 + k] = acc;
}

// ---------- 3) wq = h @ Wlin^T  (fp32, [b][768]) for user & item ----------
__global__ void wq_kernel(const float* __restrict__ uh, const float* __restrict__ ih,
                          const float* __restrict__ Wu, const float* __restrict__ Wi,
                          float* __restrict__ wqu, float* __restrict__ wqi) {
    int bx = blockIdx.x;            // 384 blocks: br(2) x b(64) x chunk(3)
    int chunk = bx % 3;
    int b = (bx / 3) & 63;
    int br = bx / 192;
    const float* h = (br == 0 ? uh : ih) + b * 768;
    const float* Wl = (br == 0 ? Wu : Wi);
    float* dst = (br == 0 ? wqu : wqi);
    __shared__ float hs[768];
    for (int i = threadIdx.x; i < 768; i += 256) hs[i] = h[i];
    __syncthreads();
    int o = chunk * 256 + threadIdx.x;
    const float4* wrow = (const float4*)(Wl + o * 768);
    float acc = 0.0f;
#pragma unroll 4
    for (int c = 0; c < 192; ++c) {
        float4 w = wrow[c];
        acc += w.x * hs[c * 4] + w.y * hs[c * 4 + 1] + w.z * hs[c * 4 + 2] + w.w * hs[c * 4 + 3];
    }
    dst[b * 768 + o] = acc;
}

// ---------- 4) W_total[b][o][k] bf16 = W_eff[o][k] + VU[k%24,o%32]*wq_u[b,k/24,o/32] + VI*wq_i ----------
__global__ void build_kernel(const float* __restrict__ Weff, const float* __restrict__ VU,
                             const float* __restrict__ VI, const float* __restrict__ wqu,
                             const float* __restrict__ wqi, unsigned short* __restrict__ Wt) {
    int bx = blockIdx.x;            // 49152 = b(64) x o(768)
    int o = bx % 768;
    int b = bx / 768;
    int m = o & 31, l = o >> 5;
    __shared__ float vu_s[24], vi_s[24], wu_s[32], wi_s[32];
    int t = threadIdx.x;
    if (t < 24) vu_s[t] = VU[t * 32 + m];
    else if (t < 48) vi_s[t - 24] = VI[(t - 24) * 32 + m];
    else if (t < 80) wu_s[t - 48] = wqu[b * 768 + (t - 48) * 24 + l];
    else if (t < 112) wi_s[t - 80] = wqi[b * 768 + (t - 80) * 24 + l];
    __syncthreads();
    size_t base = (size_t)bx * 768;
#pragma unroll
    for (int kc = 0; kc < 3; ++kc) {
        int k = kc * 256 + t;
        int q = (k * 2731) >> 16;   // k/24 for k<768
        int n = k - q * 24;
        float v = Weff[o * 768 + k] + vu_s[n] * wu_s[q] + vi_s[n] * wi_s[q];
        Wt[base + k] = f2bf(v);
    }
}

// ---------- 5) batched GEMM: out[b] = x_bf16[b] @ W_total[b] + bias ----------
// 128x128 tile, BK=64, mfma_f32_16x16x32_bf16, global_load_lds(16B) both tiles,
// XOR swizzle at 16B granularity: chunk c of row r lives at physical slot c^(r&7).
__global__ __launch_bounds__(256, 2) void gemm_kernel(
    const unsigned short* __restrict__ Xb, const unsigned short* __restrict__ Wt,
    const float* __restrict__ bias, float* __restrict__ out) {
    __shared__ __align__(16) unsigned short As[128 * 64];
    __shared__ __align__(16) unsigned short Bs[128 * 64];
    const int tid = threadIdx.x;
    const int wave = tid >> 6, lane = tid & 63;
    const int b = blockIdx.z, mt = blockIdx.y, nt = blockIdx.x;
    const int s0 = mt * 128, n0 = nt * 128;
    const unsigned short* Ab = Xb + (size_t)(b * 256 + s0) * 768;
    const unsigned short* Bb = Wt + (size_t)(b * 768 + n0) * 768;
    const int wm = wave & 1, wn = wave >> 1;

    f32x4 acc[4][4] = {};

    const int lrow = lane >> 3;   // staging: local row within 8-row group
    const int lcp = lane & 7;     // staging: physical 16B chunk slot

    for (int kk = 0; kk < 768; kk += 64) {
#pragma unroll
        for (int u = 0; u < 4; ++u) {
            int tA = wave * 4 + u;             // 0..15, 8 rows each
            int r = tA * 8 + lrow;             // 0..127
            int c = lcp ^ (r & 7);             // logical chunk fetched into slot lcp
            load_lds_16(Ab + (size_t)r * 768 + kk + c * 8, (void*)(As + tA * 512));
            load_lds_16(Bb + (size_t)r * 768 + kk + c * 8, (void*)(Bs + tA * 512));
        }
        __syncthreads();
#pragma unroll
        for (int h = 0; h < 2; ++h) {
            const int cb = h * 4 + (lane >> 4);  // logical chunk: k = cb*8 + j
            const int rl = lane & 15;
            bf16x8 af[4], bfr[4];
#pragma unroll
            for (int i = 0; i < 4; ++i) {
                int r = wm * 64 + i * 16 + rl;
                int c = cb ^ (r & 7);
                af[i] = *(const bf16x8*)(As + r * 64 + c * 8);
            }
#pragma unroll
            for (int j = 0; j < 4; ++j) {
                int r = wn * 64 + j * 16 + rl;
                int c = cb ^ (r & 7);
                bfr[j] = *(const bf16x8*)(Bs + r * 64 + c * 8);
            }
#pragma unroll
            for (int i = 0; i < 4; ++i)
#pragma unroll
                for (int j = 0; j < 4; ++j)
                    acc[i][j] = __builtin_amdgcn_mfma_f32_16x16x32_bf16(af[i], bfr[j], acc[i][j], 0, 0, 0);
        }
        __syncthreads();
    }

    // epilogue: C/D layout col=lane&15, row=(lane>>4)*4+reg (m89-verified)
    const int cl = lane & 15, rq = lane >> 4;
#pragma unroll
    for (int j = 0; j < 4; ++j) {
        int n = n0 + wn * 64 + j * 16 + cl;
        float bv = bias[n];
#pragma unroll
        for (int i = 0; i < 4; ++i) {
            int mrow = s0 + wm * 64 + i * 16 + rq * 4;
            float* op = out + (size_t)(b * 256 + mrow) * 768 + n;
#pragma unroll
            for (int g = 0; g < 4; ++g) op[(size_t)g * 768] = acc[i][j][g] + bv;
        }
    }
}

// ---------- fallback (small ws): naive fp32 ----------
__global__ void naive_kernel(const float* __restrict__ x, const float* __restrict__ Weff,
                             const float* __restrict__ wqu, const float* __restrict__ wqi,
                             const float* __restrict__ VU, const float* __restrict__ VI,
                             const float* __restrict__ bias, float* __restrict__ out) {
    int bs_ = blockIdx.x / 3;     // b*256+s
    int chunk = blockIdx.x % 3;
    int b = bs_ >> 8;
    __shared__ float xs[768];
    for (int i = threadIdx.x; i < 768; i += 256) xs[i] = x[(size_t)bs_ * 768 + i];
    __syncthreads();
    int o = chunk * 256 + threadIdx.x;
    int m = o & 31, l = o >> 5;
    float acc = bias[o];
    for (int q = 0; q < 32; ++q) {
        float wu = wqu[b * 768 + q * 24 + l];
        float wi = wqi[b * 768 + q * 24 + l];
#pragma unroll
        for (int n = 0; n < 24; ++n) {
            int k = q * 24 + n;
            float w = Weff[o * 768 + k] + VU[n * 32 + m] * wu + VI[n * 32 + m] * wi;
            acc += xs[k] * w;
        }
    }
    out[(size_t)bs_ * 768 + o] = acc;
}

extern "C" void kernel_launch(void* const* d_in, const int* in_sizes, int n_in,
                              void* d_out, int out_size, void* d_ws, size_t ws_size,
                              hipStream_t stream) {
    const float* x  = (const float*)d_in[0];
    const float* uh = (const float*)d_in[1];
    const float* ih = (const float*)d_in[2];
    const float* W  = (const float*)d_in[3];
    const float* bv = (const float*)d_in[4];
    const float* A  = (const float*)d_in[5];
    const float* B  = (const float*)d_in[6];
    const float* Wu = (const float*)d_in[7];
    const float* VU = (const float*)d_in[8];
    const float* Wi = (const float*)d_in[9];
    const float* VI = (const float*)d_in[10];
    float* out = (float*)d_out;

    const size_t off_xb   = 0;                       // 12582912 * 2 = 25165824
    const size_t off_wt   = 25165824;                // 37748736 * 2 = 75497472
    const size_t off_weff = off_wt + 75497472;       // 589824 * 4
    const size_t off_wqu  = off_weff + 2359296;      // 49152 * 4
    const size_t off_wqi  = off_wqu + 196608;
    const size_t need     = off_wqi + 196608;        // 103,415,808 B

    char* ws = (char*)d_ws;
    if (ws_size >= need) {
        unsigned short* xb  = (unsigned short*)(ws + off_xb);
        unsigned short* wt  = (unsigned short*)(ws + off_wt);
        float* weff = (float*)(ws + off_weff);
        float* wqu  = (float*)(ws + off_wqu);
        float* wqi  = (float*)(ws + off_wqi);
        conv_x_kernel<<<6144, 256, 0, stream>>>(x, xb);
        weff_kernel<<<2304, 256, 0, stream>>>(W, A, B, weff);
        wq_kernel<<<384, 256, 0, stream>>>(uh, ih, Wu, Wi, wqu, wqi);
        build_kernel<<<49152, 256, 0, stream>>>(weff, VU, VI, wqu, wqi, wt);
        gemm_kernel<<<dim3(6, 2, 64), 256, 0, stream>>>(xb, wt, bv, out);
    } else {
        float* weff = (float*)ws;
        float* wqu  = weff + 589824;
        float* wqi  = wqu + 49152;
        weff_kernel<<<2304, 256, 0, stream>>>(W, A, B, weff);
        wq_kernel<<<384, 256, 0, stream>>>(uh, ih, Wu, Wi, wqu, wqi);
        naive_kernel<<<49152, 256, 0, stream>>>(x, weff, wqu, wqi, VU, VI, bv, out);
    }
}